// Round 3
// baseline (238.622 us; speedup 1.0000x reference)
//
#include <hip/hip_runtime.h>

// DCE-MRI eTofts forward model — 4 autonomous waves per block, barrier-free.
// param: [B,3] f32, T10: [B,1] f32, cp: [B,T] f32  ->  out: [B,T] f32
//
// Block = 256 threads = 4 waves. Each wave owns 64 consecutive rows and a
// PRIVATE LDS region; there is NO cross-wave data sharing and NO barrier.
// Intra-wave LDS write->read ordering is guaranteed by the compiler's
// may-alias analysis (it inserts lgkmcnt waits between aliasing ds ops of
// the same wave) — exactly what the single-wave version relied on after
// s_barrier elision. 4-wave blocks lift the workgroup-slot occupancy cap:
// 8 WGs x 4 waves = 32 waves/CU (was ~9 with 64-thread blocks, Occ=28%).
//
// T tiled 7 x 16: each row-tile is exactly one aligned 64 B line.
// LDS transposed [t][row] with stride LP=66:
//   compute reads  sl[t*66 + l]            -> bank (2t+l)%32, 2/bank = free
//   stage/store    sl[(4*c4+k)*66 + row]   -> bank (8c4+2k+16i+rsub)%32,
//                                             exactly 2 lanes/bank = free
// (LP=65 had a 4-way conflict here: the measured 1.83M SQ_LDS_BANK_CONFLICT.)
//
// Pipeline: prefetch tile k+1 into registers (4 float4/lane, full-line,
// nontemporal) while computing tile k from LDS.

typedef float f32x4 __attribute__((ext_vector_type(4)));

static constexpr int   Bn    = 262144;
static constexpr int   Tn    = 112;
static constexpr int   TT    = 16;         // timesteps per tile (64 B per row-tile)
static constexpr int   NT    = Tn / TT;    // 7 tiles
static constexpr int   LP    = 66;         // LDS word stride between t-rows
static constexpr float TRc   = 0.005f;
static constexpr float DELTT = 0.075f;                 // 4.5/60
static constexpr float R1R   = 4.5f;
static constexpr float SIN_A = 0.25881904510252074f;   // sin(15 deg)
static constexpr float COS_A = 0.9659258262890683f;    // cos(15 deg)

__global__ __launch_bounds__(256) void etofts_kernel(
    const float* __restrict__ param,
    const float* __restrict__ T10,
    const float* __restrict__ cp,
    float* __restrict__ out)
{
    __shared__ float lds[4][TT * LP];      // 4 x 4224 B = 16896 B per WG

    const int tid = threadIdx.x;
    const int w   = tid >> 6;              // wave id within block
    const int l   = tid & 63;              // lane
    float* __restrict__ sl = lds[w];       // wave-private LDS region

    const int b0 = blockIdx.x * 256 + w * 64;  // this wave's first row
    const int b  = b0 + l;                     // this lane's own row

    // Parameter scaling + clamping
    const float ktrans = fminf(fmaxf(param[3 * b + 0] * 0.2f, 1e-5f), 0.2f);
    const float vp     = fminf(fmaxf(param[3 * b + 1] * 0.1f, 0.0005f), 0.1f);
    const float ve     = fminf(fmaxf(param[3 * b + 2] * 0.6f, 0.04f), 0.6f);
    const float decay  = __expf(-(ktrans / ve) * DELTT);
    const float r10    = 1.0f / T10[b];

    // Per-lane load/store mapping: row = i*16 + (l>>2), c4 = l&3.
    // Each 4-lane group covers one contiguous aligned 64 B line.
    const int rsub = l >> 2;               // 0..15
    const int c4   = l & 3;                // 0..3
    const int tb   = c4 * 4;               // first timestep of this float4

    // ---- prefetch tile 0 into registers (coalesced, full-line loads) ----
    f32x4 r[4];
    #pragma unroll
    for (int i = 0; i < 4; ++i) {
        const int row = i * 16 + rsub;
        r[i] = __builtin_nontemporal_load(
            (const f32x4*)(cp + (size_t)(b0 + row) * Tn + c4 * 4));
    }

    float c = 0.0f;                        // IIR state across tiles

    #pragma unroll
    for (int tile = 0; tile < NT; ++tile) {
        // ---- stage prefetched registers into transposed LDS ----
        #pragma unroll
        for (int i = 0; i < 4; ++i) {
            const int row = i * 16 + rsub;
            sl[(tb + 0) * LP + row] = r[i].x;
            sl[(tb + 1) * LP + row] = r[i].y;
            sl[(tb + 2) * LP + row] = r[i].z;
            sl[(tb + 3) * LP + row] = r[i].w;
        }
        // (no barrier: wave-private LDS; compiler orders aliasing ds ops)

        // ---- issue next tile's loads NOW (hide HBM latency behind compute) ----
        if (tile + 1 < NT) {
            #pragma unroll
            for (int i = 0; i < 4; ++i) {
                const int row = i * 16 + rsub;
                r[i] = __builtin_nontemporal_load(
                    (const f32x4*)(cp + (size_t)(b0 + row) * Tn
                                   + (tile + 1) * TT + c4 * 4));
            }
        }

        // ---- compute in place (own column: no cross-lane race) ----
        #pragma unroll
        for (int t = 0; t < TT; ++t) {
            const float cpt = sl[t * LP + l];
            c = fmaf(c, decay, cpt * DELTT);             // IIR recurrence
            const float ct = fmaf(c, ktrans, vp * cpt);  // vp*cp + ce
            const float E  = __expf(-TRc * fmaf(R1R, ct, r10));
            sl[t * LP + l] = __fdividef((1.0f - E) * (SIN_A * 20.0f),
                                        fmaf(-E, COS_A, 1.0f));
        }

        // ---- coalesced full-line store from transposed LDS ----
        #pragma unroll
        for (int i = 0; i < 4; ++i) {
            const int row = i * 16 + rsub;
            f32x4 o;
            o.x = sl[(tb + 0) * LP + row];
            o.y = sl[(tb + 1) * LP + row];
            o.z = sl[(tb + 2) * LP + row];
            o.w = sl[(tb + 3) * LP + row];
            __builtin_nontemporal_store(
                o, (f32x4*)(out + (size_t)(b0 + row) * Tn + tile * TT + c4 * 4));
        }
        // (no barrier: next stage's ds_writes are ordered after these ds_reads
        //  by the compiler's WAR handling within the wave)
    }
}

extern "C" void kernel_launch(void* const* d_in, const int* in_sizes, int n_in,
                              void* d_out, int out_size, void* d_ws, size_t ws_size,
                              hipStream_t stream) {
    const float* param = (const float*)d_in[0];
    const float* T10   = (const float*)d_in[1];
    const float* cp    = (const float*)d_in[2];
    float*       out   = (float*)d_out;

    const int threads = 256;
    const int blocks  = Bn / 256;          // 1024 four-wave workgroups
    etofts_kernel<<<blocks, threads, 0, stream>>>(param, T10, cp, out);
}

// Round 4
// 228.290 us; speedup vs baseline: 1.0453x; 1.0453x over previous
//
#include <hip/hip_runtime.h>

// DCE-MRI eTofts forward model — full-row register prefetch, barrier-free.
// param: [B,3] f32, T10: [B,1] f32, cp: [B,T] f32  ->  out: [B,T] f32
//
// Grid has only 4096 waves total (16/CU) — TLP is capped by problem size, so
// latency hiding must come from ILP: each wave issues ALL 28 of its row-tile
// loads (7 tiles x 4 float4/lane = 112 VGPRs) at kernel start. Every tile's
// staging then waits on a constant vmcnt(24): its 4 loads are the OLDEST
// outstanding VMEM entries, and result stores (issued later, younger) never
// block the wait. HBM latency is paid once per wave, not once per tile.
//
// Block = 128 threads = 2 autonomous waves, each owning 64 rows + a private
// LDS region; no barriers (intra-wave DS ordering is in-order per the DS
// pipe; correctness precedent: R3 kernel passed barrier-free).
// 2048 WGs = 8 WGs/CU dispatch granularity (was 4/CU) -> less tail skew.
//
// T tiled 7 x 16: each row-tile is one aligned 64 B line per row.
// LDS transposed [t][row], stride LP=66 (both access phases exactly
// 2 lanes/bank = conflict-free; verified SQ_LDS_BANK_CONFLICT=0 in R3).
//
// All loop indices are compile-time constants after unrolling, so r[28]
// stays in registers (runtime-indexed ext_vector arrays would spill).

typedef float f32x4 __attribute__((ext_vector_type(4)));

static constexpr int   Bn    = 262144;
static constexpr int   Tn    = 112;
static constexpr int   TT    = 16;         // timesteps per tile (64 B per row-tile)
static constexpr int   NT    = Tn / TT;    // 7 tiles
static constexpr int   LP    = 66;         // LDS word stride between t-rows
static constexpr float TRc   = 0.005f;
static constexpr float DELTT = 0.075f;                 // 4.5/60
static constexpr float R1R   = 4.5f;
static constexpr float SIN_A = 0.25881904510252074f;   // sin(15 deg)
static constexpr float COS_A = 0.9659258262890683f;    // cos(15 deg)

__global__ __launch_bounds__(128) void etofts_kernel(
    const float* __restrict__ param,
    const float* __restrict__ T10,
    const float* __restrict__ cp,
    float* __restrict__ out)
{
    __shared__ float lds[2][TT * LP];      // 2 x 4224 B = 8448 B per WG

    const int tid = threadIdx.x;
    const int w   = tid >> 6;              // wave id within block
    const int l   = tid & 63;              // lane
    float* __restrict__ sl = lds[w];       // wave-private LDS region

    const int b0 = blockIdx.x * 128 + w * 64;  // this wave's first row
    const int b  = b0 + l;                     // this lane's own row

    // Per-lane load/store mapping: row = i*16 + (l>>2), c4 = l&3.
    // Each 4-lane group covers one contiguous aligned 64 B line.
    const int rsub = l >> 2;               // 0..15
    const int c4   = l & 3;                // 0..3
    const int tb   = c4 * 4;               // first timestep of this float4

    // ---- issue ALL row loads up front: 7 tiles x 4 full-line float4 ----
    f32x4 r[NT * 4];                       // 112 VGPRs of in-flight data
    #pragma unroll
    for (int k = 0; k < NT; ++k) {         // tile-major: oldest = tile 0
        #pragma unroll
        for (int i = 0; i < 4; ++i) {
            const int row = i * 16 + rsub;
            r[k * 4 + i] = __builtin_nontemporal_load(
                (const f32x4*)(cp + (size_t)(b0 + row) * Tn + k * TT + c4 * 4));
        }
    }

    // Parameter scaling + clamping (loads issued after cp block; they
    // complete early regardless — tiny)
    const float ktrans = fminf(fmaxf(param[3 * b + 0] * 0.2f, 1e-5f), 0.2f);
    const float vp     = fminf(fmaxf(param[3 * b + 1] * 0.1f, 0.0005f), 0.1f);
    const float ve     = fminf(fmaxf(param[3 * b + 2] * 0.6f, 0.04f), 0.6f);
    const float decay  = __expf(-(ktrans / ve) * DELTT);
    const float r10    = 1.0f / T10[b];

    float c = 0.0f;                        // IIR state across tiles

    #pragma unroll
    for (int tile = 0; tile < NT; ++tile) {
        // ---- stage this tile's registers into transposed LDS ----
        // (waits only on the 4 oldest outstanding loads: constant vmcnt)
        #pragma unroll
        for (int i = 0; i < 4; ++i) {
            const int row = i * 16 + rsub;
            const f32x4 v = r[tile * 4 + i];
            sl[(tb + 0) * LP + row] = v.x;
            sl[(tb + 1) * LP + row] = v.y;
            sl[(tb + 2) * LP + row] = v.z;
            sl[(tb + 3) * LP + row] = v.w;
        }
        // (no barrier: wave-private LDS; DS pipe is in-order within a wave)

        // ---- compute in place (own column: no cross-lane race) ----
        #pragma unroll
        for (int t = 0; t < TT; ++t) {
            const float cpt = sl[t * LP + l];
            c = fmaf(c, decay, cpt * DELTT);             // IIR recurrence
            const float ct = fmaf(c, ktrans, vp * cpt);  // vp*cp + ce
            const float E  = __expf(-TRc * fmaf(R1R, ct, r10));
            sl[t * LP + l] = __fdividef((1.0f - E) * (SIN_A * 20.0f),
                                        fmaf(-E, COS_A, 1.0f));
        }

        // ---- coalesced full-line store from transposed LDS ----
        #pragma unroll
        for (int i = 0; i < 4; ++i) {
            const int row = i * 16 + rsub;
            f32x4 o;
            o.x = sl[(tb + 0) * LP + row];
            o.y = sl[(tb + 1) * LP + row];
            o.z = sl[(tb + 2) * LP + row];
            o.w = sl[(tb + 3) * LP + row];
            __builtin_nontemporal_store(
                o, (f32x4*)(out + (size_t)(b0 + row) * Tn + tile * TT + c4 * 4));
        }
        // (no barrier: next stage's ds_writes are WAR-ordered by the DS pipe)
    }
}

extern "C" void kernel_launch(void* const* d_in, const int* in_sizes, int n_in,
                              void* d_out, int out_size, void* d_ws, size_t ws_size,
                              hipStream_t stream) {
    const float* param = (const float*)d_in[0];
    const float* T10   = (const float*)d_in[1];
    const float* cp    = (const float*)d_in[2];
    float*       out   = (float*)d_out;

    const int threads = 128;
    const int blocks  = Bn / 128;          // 2048 two-wave workgroups
    etofts_kernel<<<blocks, threads, 0, stream>>>(param, T10, cp, out);
}